// Round 6
// baseline (158.109 us; speedup 1.0000x reference)
//
#include <hip/hip_runtime.h>
#include <cfloat>
#include <cstdint>

#define K 8
#define NT 256
#define NW (NT / 64)
#define CH2B 4   // gated 4-deep batches before the 2nd refresh

typedef float f32x4 __attribute__((ext_vector_type(4)));

__global__ __launch_bounds__(NT) void topk8_kernel(const float* __restrict__ x,
                                                   float* __restrict__ out,
                                                   int ncols, int nrows) {
    const int row  = blockIdx.x;
    const int tid  = threadIdx.x;
    const int lane = tid & 63;
    const int wave = tid >> 6;
    const float* __restrict__ rowp = x + (size_t)row * (size_t)ncols;

    __shared__ float swv[NW * K];   // refresh scratch + final candidate values
    __shared__ int   swi[NW * K];   // final candidate indices

    // Per-thread top-8, sorted descending; compile-time indices only (VGPRs).
    float v[K];
    int   id[K];
#pragma unroll
    for (int i = 0; i < K; ++i) { v[i] = -FLT_MAX; id[i] = 0x7fffffff; }

    auto insert = [&](float val, int idx) {
        if (val > v[K - 1]) {
            v[K - 1] = val; id[K - 1] = idx;
#pragma unroll
            for (int p = K - 1; p > 0; --p) {
                // bubbles only past strictly-smaller values -> ties keep
                // ascending-index order (stable like lax.top_k)
                if (v[p] > v[p - 1]) {
                    float tv = v[p]; v[p] = v[p - 1]; v[p - 1] = tv;
                    int   ti = id[p]; id[p] = id[p - 1]; id[p - 1] = ti;
                }
            }
        }
    };

    // Block-wide "8th largest of everything retained so far" — provable lower
    // bound on the row's final 8th value (8th of subset <= 8th of superset).
    auto refresh = [&](float Told) -> float {
        float t0 = v[0], t1 = v[1], t2 = v[2], t3 = v[3];
        float t4 = v[4], t5 = v[5], t6 = v[6], t7 = v[7];
#pragma unroll
        for (int r = 0; r < K; ++r) {
            float m = t0;
#pragma unroll
            for (int off = 32; off >= 1; off >>= 1)
                m = fmaxf(m, __shfl_xor(m, off));
            const bool pop = (t0 == m);   // ties pop together: T only shrinks
            t0 = pop ? t1 : t0;
            t1 = pop ? t2 : t1;
            t2 = pop ? t3 : t2;
            t3 = pop ? t4 : t3;
            t4 = pop ? t5 : t4;
            t5 = pop ? t6 : t5;
            t6 = pop ? t7 : t6;
            t7 = pop ? -FLT_MAX : t7;
            if (lane == 0) swv[wave * K + r] = m;
        }
        __syncthreads();
        float g0 = -FLT_MAX, g1 = -FLT_MAX, g2 = -FLT_MAX, g3 = -FLT_MAX;
        float g4 = -FLT_MAX, g5 = -FLT_MAX, g6 = -FLT_MAX, g7 = -FLT_MAX;
#pragma unroll
        for (int i = 0; i < NW * K; ++i) {
            const float xx = swv[i];
            g7 = __builtin_amdgcn_fmed3f(g6, g7, xx);
            g6 = __builtin_amdgcn_fmed3f(g5, g6, xx);
            g5 = __builtin_amdgcn_fmed3f(g4, g5, xx);
            g4 = __builtin_amdgcn_fmed3f(g3, g4, xx);
            g3 = __builtin_amdgcn_fmed3f(g2, g3, xx);
            g2 = __builtin_amdgcn_fmed3f(g1, g2, xx);
            g1 = __builtin_amdgcn_fmed3f(g0, g1, xx);
            g0 = fmaxf(g0, xx);
        }
        __syncthreads();   // protect swv for later reuse
        return fmaxf(Told, g7);
    };

    // Alignment prologue: align the vector stream to 128 B (full L2 lines) so
    // every wave's 1 KB request is exactly 8 cache lines. head <= 31, scalar.
    const int mis  = (int)(((uintptr_t)rowp >> 2) & 31);   // elements mod 32
    int head = (32 - mis) & 31;
    if (head > ncols) head = ncols;
    if (tid < head) insert(rowp[tid], tid);

    const int nvec4 = (ncols - head) >> 2;
    const f32x4* __restrict__ vp = (const f32x4*)(rowp + head);

    int j = tid;

    // Gated 4-deep batch: 4 plain dwordx4 loads in flight per lane.
    // (A/B vs round 5: identical except loads are NOT nontemporal.)
    float T = -FLT_MAX;
    auto gated4 = [&](int jj) {
        f32x4 f0 = vp[jj];
        f32x4 f1 = vp[jj + NT];
        f32x4 f2 = vp[jj + 2 * NT];
        f32x4 f3 = vp[jj + 3 * NT];
        const float m0 = fmaxf(fmaxf(f0[0], f0[1]), fmaxf(f0[2], f0[3]));
        const float m1 = fmaxf(fmaxf(f1[0], f1[1]), fmaxf(f1[2], f1[3]));
        const float m2 = fmaxf(fmaxf(f2[0], f2[1]), fmaxf(f2[2], f2[3]));
        const float m3 = fmaxf(fmaxf(f3[0], f3[1]), fmaxf(f3[2], f3[3]));
        const float mm = fmaxf(fmaxf(m0, m1), fmaxf(m2, m3));
        if (mm >= T) {
            if (m0 >= T) {
                const int b = head + 4 * jj;
                if (f0[0] >= T) insert(f0[0], b);
                if (f0[1] >= T) insert(f0[1], b + 1);
                if (f0[2] >= T) insert(f0[2], b + 2);
                if (f0[3] >= T) insert(f0[3], b + 3);
            }
            if (m1 >= T) {
                const int b = head + 4 * (jj + NT);
                if (f1[0] >= T) insert(f1[0], b);
                if (f1[1] >= T) insert(f1[1], b + 1);
                if (f1[2] >= T) insert(f1[2], b + 2);
                if (f1[3] >= T) insert(f1[3], b + 3);
            }
            if (m2 >= T) {
                const int b = head + 4 * (jj + 2 * NT);
                if (f2[0] >= T) insert(f2[0], b);
                if (f2[1] >= T) insert(f2[1], b + 1);
                if (f2[2] >= T) insert(f2[2], b + 2);
                if (f2[3] >= T) insert(f2[3], b + 3);
            }
            if (m3 >= T) {
                const int b = head + 4 * (jj + 3 * NT);
                if (f3[0] >= T) insert(f3[0], b);
                if (f3[1] >= T) insert(f3[1], b + 1);
                if (f3[2] >= T) insert(f3[2], b + 2);
                if (f3[3] >= T) insert(f3[3], b + 3);
            }
        }
    };

    // Warmup (ungated): one 4-deep batch, same MLP as steady state.
    if (j + 3 * NT < nvec4) {
        f32x4 f0 = vp[j];
        f32x4 f1 = vp[j + NT];
        f32x4 f2 = vp[j + 2 * NT];
        f32x4 f3 = vp[j + 3 * NT];
        int b = head + 4 * j;
        insert(f0[0], b); insert(f0[1], b + 1); insert(f0[2], b + 2); insert(f0[3], b + 3);
        b = head + 4 * (j + NT);
        insert(f1[0], b); insert(f1[1], b + 1); insert(f1[2], b + 2); insert(f1[3], b + 3);
        b = head + 4 * (j + 2 * NT);
        insert(f2[0], b); insert(f2[1], b + 1); insert(f2[2], b + 2); insert(f2[3], b + 3);
        b = head + 4 * (j + 3 * NT);
        insert(f3[0], b); insert(f3[1], b + 1); insert(f3[2], b + 2); insert(f3[3], b + 3);
        j += 4 * NT;
    } else {
        for (int w = 0; w < 4 && j < nvec4; ++w, j += NT) {
            f32x4 f = vp[j];
            const int b = head + 4 * j;
            insert(f[0], b); insert(f[1], b + 1); insert(f[2], b + 2); insert(f[3], b + 3);
        }
    }

    T = refresh(-FLT_MAX);

    // Chunk 2 (gated, 4-deep).
    for (int bk = 0; bk < CH2B; ++bk) {
        if (j + 3 * NT < nvec4) {
            gated4(j);
            j += 4 * NT;
        } else {
            for (int w = 0; w < 4 && j < nvec4; ++w, j += NT) {
                f32x4 f = vp[j];
                const float m = fmaxf(fmaxf(f[0], f[1]), fmaxf(f[2], f[3]));
                if (m >= T) {
                    const int b = head + 4 * j;
                    if (f[0] >= T) insert(f[0], b);
                    if (f[1] >= T) insert(f[1], b + 1);
                    if (f[2] >= T) insert(f[2], b + 2);
                    if (f[3] >= T) insert(f[3], b + 3);
                }
            }
        }
    }

    T = refresh(T);

    // Chunk 3: steady state, gated 4-deep.
    for (; j + 3 * NT < nvec4; j += 4 * NT) gated4(j);

    // Remainder float4s.
    for (; j < nvec4; j += NT) {
        f32x4 f = vp[j];
        const float m = fmaxf(fmaxf(f[0], f[1]), fmaxf(f[2], f[3]));
        if (m >= T) {
            const int b = head + 4 * j;
            if (f[0] >= T) insert(f[0], b);
            if (f[1] >= T) insert(f[1], b + 1);
            if (f[2] >= T) insert(f[2], b + 2);
            if (f[3] >= T) insert(f[3], b + 3);
        }
    }

    // Scalar tail.
    const int tb = head + 4 * nvec4;
    for (int c = tb + tid; c < ncols; c += NT) insert(rowp[c], c);

    // ---- Final merge, barrier-light ----
    // Stage 1: per-wave top-8 via 8 rounds of 64-lane shuffle-argmax +
    // owner-pop. No barriers. Tie-break: smaller index wins.
#pragma unroll
    for (int r = 0; r < K; ++r) {
        float bv = v[0];
        int   bi = id[0];
        int   bt = lane;
#pragma unroll
        for (int off = 32; off >= 1; off >>= 1) {
            float ov = __shfl_xor(bv, off);
            int   oi = __shfl_xor(bi, off);
            int   ot = __shfl_xor(bt, off);
            if (ov > bv || (ov == bv && oi < bi)) { bv = ov; bi = oi; bt = ot; }
        }
        if (lane == bt) {   // butterfly result is wave-uniform; owner pops head
#pragma unroll
            for (int p = 0; p < K - 1; ++p) { v[p] = v[p + 1]; id[p] = id[p + 1]; }
            v[K - 1] = -FLT_MAX; id[K - 1] = 0x7fffffff;
        }
        if (lane == 0) { swv[wave * K + r] = bv; swi[wave * K + r] = bi; }
    }
    __syncthreads();

    // Stage 2: wave 0 merges the 32 candidates (lanes 32-63 padded) with 8
    // more butterfly rounds; lane 0 stores directly.
    if (wave == 0) {
        float cv = (lane < NW * K) ? swv[lane] : -FLT_MAX;
        int   ci = (lane < NW * K) ? swi[lane] : 0x7fffffff;
#pragma unroll
        for (int r = 0; r < K; ++r) {
            float bv = cv;
            int   bi = ci;
            int   bt = lane;
#pragma unroll
            for (int off = 32; off >= 1; off >>= 1) {
                float ov = __shfl_xor(bv, off);
                int   oi = __shfl_xor(bi, off);
                int   ot = __shfl_xor(bt, off);
                if (ov > bv || (ov == bv && oi < bi)) { bv = ov; bi = oi; bt = ot; }
            }
            if (lane == bt) { cv = -FLT_MAX; ci = 0x7fffffff; }
            if (lane == 0) {
                out[(size_t)row * K + r]                     = bv;
                out[(size_t)nrows * K + (size_t)row * K + r] = (float)bi;
            }
        }
    }
}

extern "C" void kernel_launch(void* const* d_in, const int* in_sizes, int n_in,
                              void* d_out, int out_size, void* d_ws, size_t ws_size,
                              hipStream_t stream) {
    const float* x = (const float*)d_in[0];
    float* out = (float*)d_out;
    const int nrows = 4096;
    const int ncols = in_sizes[0] / nrows;   // 50257
    topk8_kernel<<<nrows, NT, 0, stream>>>(x, out, ncols, nrows);
}

// Round 7
// 145.153 us; speedup vs baseline: 1.0893x; 1.0893x over previous
//
#include <hip/hip_runtime.h>
#include <cfloat>
#include <cstdint>

#define K 8
#define NT 256
#define NW (NT / 64)
#define CH2B 4   // gated 4-deep batches before the 2nd refresh

typedef float f32x4 __attribute__((ext_vector_type(4)));

__global__ __launch_bounds__(NT) void topk8_kernel(const float* __restrict__ x,
                                                   float* __restrict__ out,
                                                   int ncols, int nrows) {
    const int row  = blockIdx.x;
    const int tid  = threadIdx.x;
    const int lane = tid & 63;
    const int wave = tid >> 6;
    const float* __restrict__ rowp = x + (size_t)row * (size_t)ncols;

    __shared__ float swv[NW * K];   // refresh scratch + final candidate values
    __shared__ int   swi[NW * K];   // final candidate indices

    // Per-thread top-8, sorted descending; compile-time indices only (VGPRs).
    float v[K];
    int   id[K];
#pragma unroll
    for (int i = 0; i < K; ++i) { v[i] = -FLT_MAX; id[i] = 0x7fffffff; }

    auto insert = [&](float val, int idx) {
        if (val > v[K - 1]) {
            v[K - 1] = val; id[K - 1] = idx;
#pragma unroll
            for (int p = K - 1; p > 0; --p) {
                // bubbles only past strictly-smaller values -> ties keep
                // ascending-index order (stable like lax.top_k)
                if (v[p] > v[p - 1]) {
                    float tv = v[p]; v[p] = v[p - 1]; v[p - 1] = tv;
                    int   ti = id[p]; id[p] = id[p - 1]; id[p - 1] = ti;
                }
            }
        }
    };

    // Block-wide "8th largest of everything retained so far" — provable lower
    // bound on the row's final 8th value (8th of subset <= 8th of superset).
    auto refresh = [&](float Told) -> float {
        float t0 = v[0], t1 = v[1], t2 = v[2], t3 = v[3];
        float t4 = v[4], t5 = v[5], t6 = v[6], t7 = v[7];
#pragma unroll
        for (int r = 0; r < K; ++r) {
            float m = t0;
#pragma unroll
            for (int off = 32; off >= 1; off >>= 1)
                m = fmaxf(m, __shfl_xor(m, off));
            const bool pop = (t0 == m);   // ties pop together: T only shrinks
            t0 = pop ? t1 : t0;
            t1 = pop ? t2 : t1;
            t2 = pop ? t3 : t2;
            t3 = pop ? t4 : t3;
            t4 = pop ? t5 : t4;
            t5 = pop ? t6 : t5;
            t6 = pop ? t7 : t6;
            t7 = pop ? -FLT_MAX : t7;
            if (lane == 0) swv[wave * K + r] = m;
        }
        __syncthreads();
        float g0 = -FLT_MAX, g1 = -FLT_MAX, g2 = -FLT_MAX, g3 = -FLT_MAX;
        float g4 = -FLT_MAX, g5 = -FLT_MAX, g6 = -FLT_MAX, g7 = -FLT_MAX;
#pragma unroll
        for (int i = 0; i < NW * K; ++i) {
            const float xx = swv[i];
            g7 = __builtin_amdgcn_fmed3f(g6, g7, xx);
            g6 = __builtin_amdgcn_fmed3f(g5, g6, xx);
            g5 = __builtin_amdgcn_fmed3f(g4, g5, xx);
            g4 = __builtin_amdgcn_fmed3f(g3, g4, xx);
            g3 = __builtin_amdgcn_fmed3f(g2, g3, xx);
            g2 = __builtin_amdgcn_fmed3f(g1, g2, xx);
            g1 = __builtin_amdgcn_fmed3f(g0, g1, xx);
            g0 = fmaxf(g0, xx);
        }
        __syncthreads();   // protect swv for later reuse
        return fmaxf(Told, g7);
    };

    // Alignment prologue: align the vector stream to 128 B (full L2 lines) so
    // every wave's 1 KB request is exactly 8 cache lines — no partial-line
    // over-fetch under nontemporal loads. head <= 31 elements, scalar.
    const int mis  = (int)(((uintptr_t)rowp >> 2) & 31);   // elements mod 32
    int head = (32 - mis) & 31;
    if (head > ncols) head = ncols;
    if (tid < head) insert(rowp[tid], tid);

    const int nvec4 = (ncols - head) >> 2;
    const f32x4* __restrict__ vp = (const f32x4*)(rowp + head);

    int j = tid;

    // Gated 4-deep batch: 4 nontemporal dwordx4 loads in flight per lane.
    float T = -FLT_MAX;
    auto gated4 = [&](int jj) {
        f32x4 f0 = __builtin_nontemporal_load(vp + jj);
        f32x4 f1 = __builtin_nontemporal_load(vp + jj + NT);
        f32x4 f2 = __builtin_nontemporal_load(vp + jj + 2 * NT);
        f32x4 f3 = __builtin_nontemporal_load(vp + jj + 3 * NT);
        const float m0 = fmaxf(fmaxf(f0[0], f0[1]), fmaxf(f0[2], f0[3]));
        const float m1 = fmaxf(fmaxf(f1[0], f1[1]), fmaxf(f1[2], f1[3]));
        const float m2 = fmaxf(fmaxf(f2[0], f2[1]), fmaxf(f2[2], f2[3]));
        const float m3 = fmaxf(fmaxf(f3[0], f3[1]), fmaxf(f3[2], f3[3]));
        const float mm = fmaxf(fmaxf(m0, m1), fmaxf(m2, m3));
        if (mm >= T) {
            if (m0 >= T) {
                const int b = head + 4 * jj;
                if (f0[0] >= T) insert(f0[0], b);
                if (f0[1] >= T) insert(f0[1], b + 1);
                if (f0[2] >= T) insert(f0[2], b + 2);
                if (f0[3] >= T) insert(f0[3], b + 3);
            }
            if (m1 >= T) {
                const int b = head + 4 * (jj + NT);
                if (f1[0] >= T) insert(f1[0], b);
                if (f1[1] >= T) insert(f1[1], b + 1);
                if (f1[2] >= T) insert(f1[2], b + 2);
                if (f1[3] >= T) insert(f1[3], b + 3);
            }
            if (m2 >= T) {
                const int b = head + 4 * (jj + 2 * NT);
                if (f2[0] >= T) insert(f2[0], b);
                if (f2[1] >= T) insert(f2[1], b + 1);
                if (f2[2] >= T) insert(f2[2], b + 2);
                if (f2[3] >= T) insert(f2[3], b + 3);
            }
            if (m3 >= T) {
                const int b = head + 4 * (jj + 3 * NT);
                if (f3[0] >= T) insert(f3[0], b);
                if (f3[1] >= T) insert(f3[1], b + 1);
                if (f3[2] >= T) insert(f3[2], b + 2);
                if (f3[3] >= T) insert(f3[3], b + 3);
            }
        }
    };

    // Warmup (ungated): one 4-deep batch, same MLP as steady state.
    if (j + 3 * NT < nvec4) {
        f32x4 f0 = __builtin_nontemporal_load(vp + j);
        f32x4 f1 = __builtin_nontemporal_load(vp + j + NT);
        f32x4 f2 = __builtin_nontemporal_load(vp + j + 2 * NT);
        f32x4 f3 = __builtin_nontemporal_load(vp + j + 3 * NT);
        int b = head + 4 * j;
        insert(f0[0], b); insert(f0[1], b + 1); insert(f0[2], b + 2); insert(f0[3], b + 3);
        b = head + 4 * (j + NT);
        insert(f1[0], b); insert(f1[1], b + 1); insert(f1[2], b + 2); insert(f1[3], b + 3);
        b = head + 4 * (j + 2 * NT);
        insert(f2[0], b); insert(f2[1], b + 1); insert(f2[2], b + 2); insert(f2[3], b + 3);
        b = head + 4 * (j + 3 * NT);
        insert(f3[0], b); insert(f3[1], b + 1); insert(f3[2], b + 2); insert(f3[3], b + 3);
        j += 4 * NT;
    } else {
        for (int w = 0; w < 4 && j < nvec4; ++w, j += NT) {
            f32x4 f = vp[j];
            const int b = head + 4 * j;
            insert(f[0], b); insert(f[1], b + 1); insert(f[2], b + 2); insert(f[3], b + 3);
        }
    }

    T = refresh(-FLT_MAX);

    // Chunk 2 (gated, 4-deep).
    for (int bk = 0; bk < CH2B; ++bk) {
        if (j + 3 * NT < nvec4) {
            gated4(j);
            j += 4 * NT;
        } else {
            for (int w = 0; w < 4 && j < nvec4; ++w, j += NT) {
                f32x4 f = vp[j];
                const float m = fmaxf(fmaxf(f[0], f[1]), fmaxf(f[2], f[3]));
                if (m >= T) {
                    const int b = head + 4 * j;
                    if (f[0] >= T) insert(f[0], b);
                    if (f[1] >= T) insert(f[1], b + 1);
                    if (f[2] >= T) insert(f[2], b + 2);
                    if (f[3] >= T) insert(f[3], b + 3);
                }
            }
        }
    }

    T = refresh(T);

    // Chunk 3: steady state, gated 4-deep.
    for (; j + 3 * NT < nvec4; j += 4 * NT) gated4(j);

    // Remainder float4s.
    for (; j < nvec4; j += NT) {
        f32x4 f = vp[j];
        const float m = fmaxf(fmaxf(f[0], f[1]), fmaxf(f[2], f[3]));
        if (m >= T) {
            const int b = head + 4 * j;
            if (f[0] >= T) insert(f[0], b);
            if (f[1] >= T) insert(f[1], b + 1);
            if (f[2] >= T) insert(f[2], b + 2);
            if (f[3] >= T) insert(f[3], b + 3);
        }
    }

    // Scalar tail.
    const int tb = head + 4 * nvec4;
    for (int c = tb + tid; c < ncols; c += NT) insert(rowp[c], c);

    // ---- Final merge, barrier-light ----
    // Stage 1: per-wave top-8 via 8 rounds of 64-lane shuffle-argmax +
    // owner-pop. No barriers. Tie-break: smaller index wins.
#pragma unroll
    for (int r = 0; r < K; ++r) {
        float bv = v[0];
        int   bi = id[0];
        int   bt = lane;
#pragma unroll
        for (int off = 32; off >= 1; off >>= 1) {
            float ov = __shfl_xor(bv, off);
            int   oi = __shfl_xor(bi, off);
            int   ot = __shfl_xor(bt, off);
            if (ov > bv || (ov == bv && oi < bi)) { bv = ov; bi = oi; bt = ot; }
        }
        if (lane == bt) {   // butterfly result is wave-uniform; owner pops head
#pragma unroll
            for (int p = 0; p < K - 1; ++p) { v[p] = v[p + 1]; id[p] = id[p + 1]; }
            v[K - 1] = -FLT_MAX; id[K - 1] = 0x7fffffff;
        }
        if (lane == 0) { swv[wave * K + r] = bv; swi[wave * K + r] = bi; }
    }
    __syncthreads();

    // Stage 2: wave 0 merges the 32 candidates (lanes 32-63 padded) with 8
    // more butterfly rounds; lane 0 stores directly.
    if (wave == 0) {
        float cv = (lane < NW * K) ? swv[lane] : -FLT_MAX;
        int   ci = (lane < NW * K) ? swi[lane] : 0x7fffffff;
#pragma unroll
        for (int r = 0; r < K; ++r) {
            float bv = cv;
            int   bi = ci;
            int   bt = lane;
#pragma unroll
            for (int off = 32; off >= 1; off >>= 1) {
                float ov = __shfl_xor(bv, off);
                int   oi = __shfl_xor(bi, off);
                int   ot = __shfl_xor(bt, off);
                if (ov > bv || (ov == bv && oi < bi)) { bv = ov; bi = oi; bt = ot; }
            }
            if (lane == bt) { cv = -FLT_MAX; ci = 0x7fffffff; }
            if (lane == 0) {
                out[(size_t)row * K + r]                     = bv;
                out[(size_t)nrows * K + (size_t)row * K + r] = (float)bi;
            }
        }
    }
}

extern "C" void kernel_launch(void* const* d_in, const int* in_sizes, int n_in,
                              void* d_out, int out_size, void* d_ws, size_t ws_size,
                              hipStream_t stream) {
    const float* x = (const float*)d_in[0];
    float* out = (float*)d_out;
    const int nrows = 4096;
    const int ncols = in_sizes[0] / nrows;   // 50257
    topk8_kernel<<<nrows, NT, 0, stream>>>(x, out, ncols, nrows);
}